// Round 1
// baseline (235.285 us; speedup 1.0000x reference)
//
#include <hip/hip_runtime.h>

#define D 512
#define NROWS 8192
#define MROWS 8192
#define NCHUNK 8
#define CHUNK_COLS (MROWS / NCHUNK)   // 1024
#define SUBTILES (CHUNK_COLS / 128)   // 8

typedef float floatx4 __attribute__((ext_vector_type(4)));
typedef __bf16 bf16x8 __attribute__((ext_vector_type(8)));
typedef unsigned short ushortx4 __attribute__((ext_vector_type(4)));

typedef __attribute__((address_space(1))) void* as1_void_p;
typedef __attribute__((address_space(3))) void* as3_void_p;

__device__ __forceinline__ void async_cp16(const void* g, void* l) {
    __builtin_amdgcn_global_load_lds((as1_void_p)(void*)g, (as3_void_p)l, 16, 0, 0);
}

// float -> bf16 (RNE), raw bits
__device__ __forceinline__ unsigned short f2bf(float f) {
    unsigned u = __float_as_uint(f);
    u += 0x7fffu + ((u >> 16) & 1u);
    return (unsigned short)(u >> 16);
}
__device__ __forceinline__ float bf2f(unsigned short h) {
    return __uint_as_float(((unsigned)h) << 16);
}

// ---------------------------------------------------------------------------
// Kernel 1: x (fp32, row-major N x 512) -> bf16 + row sum-of-squares of the
// ROUNDED values (consistency: m = -0.5*||x~ - f~||^2 exactly).
__global__ void k_prep_x(const float* __restrict__ x,
                         unsigned short* __restrict__ xb,
                         float* __restrict__ xsq) {
    const int row = blockIdx.x;
    const int t = threadIdx.x;  // 256
    const float2 v = ((const float2*)(x + (size_t)row * D))[t];
    const unsigned short b0 = f2bf(v.x), b1 = f2bf(v.y);
    ((unsigned*)(xb + (size_t)row * D))[t] = (unsigned)b0 | ((unsigned)b1 << 16);
    const float f0 = bf2f(b0), f1 = bf2f(b1);
    float s = f0 * f0 + f1 * f1;
    #pragma unroll
    for (int m = 1; m < 64; m <<= 1) s += __shfl_xor(s, m);
    __shared__ float ws4[4];
    if ((t & 63) == 0) ws4[t >> 6] = s;
    __syncthreads();
    if (t == 0) xsq[row] = ws4[0] + ws4[1] + ws4[2] + ws4[3];
}

// ---------------------------------------------------------------------------
// Kernel 2: generic fp32 -> bf16 convert, 4 elems/thread.
__global__ void k_convert(const float* __restrict__ src,
                          unsigned short* __restrict__ dst, int n4) {
    const int i = blockIdx.x * blockDim.x + threadIdx.x;
    if (i < n4) {
        const float4 v = ((const float4*)src)[i];
        ushortx4 o;
        o.x = f2bf(v.x); o.y = f2bf(v.y); o.z = f2bf(v.z); o.w = f2bf(v.w);
        ((ushortx4*)dst)[i] = o;
    }
}

// ---------------------------------------------------------------------------
// Kernel 3: f = tanh(mu @ W^T + b), bf16 MFMA GEMM (B^T layout: both mu and W
// row-major with k=D_IN innermost). Output f_bf16 (M x 512 row-major).
// m97 structure: 128x128 tile, BK=32, 4 waves 2x2, global_load_lds width 16.
__global__ __launch_bounds__(256, 2)
void k_fgemm(const unsigned short* __restrict__ mub,
             const unsigned short* __restrict__ Wb,
             const float* __restrict__ bias,
             unsigned short* __restrict__ fb) {
    __shared__ unsigned short Ab[128 * 32];
    __shared__ unsigned short Bb[128 * 32];

    const int tid = threadIdx.x;
    const int wave = tid >> 6;
    const int lane = tid & 63;
    const int wr = wave >> 1, wc = wave & 1;
    const int g = lane >> 4;      // quad
    const int lm = lane & 15;

    const int row0 = blockIdx.x * 128;   // over M
    const int col0 = blockIdx.y * 128;   // over 512 (D_OUT)

    const unsigned short* gA = mub + (size_t)(row0 + (tid >> 2)) * D + (tid & 3) * 8;
    const unsigned short* gB = Wb  + (size_t)(col0 + (tid >> 2)) * D + (tid & 3) * 8;
    char* lA = ((char*)Ab) + wave * 1024;
    char* lB = ((char*)Bb) + wave * 1024;

    const unsigned short* fragA = Ab + (64 * wr + lm) * 32 + g * 8;
    const unsigned short* fragB = Bb + (64 * wc + lm) * 32 + g * 8;

    floatx4 acc[4][4];
    const floatx4 zz = {0.f, 0.f, 0.f, 0.f};
    #pragma unroll
    for (int i = 0; i < 4; ++i)
        #pragma unroll
        for (int j = 0; j < 4; ++j) acc[i][j] = zz;

    for (int kt = 0; kt < 16; ++kt) {
        const int k0 = kt * 32;
        async_cp16(gA + k0, lA);
        async_cp16(gA + 64 * D + k0, lA + 4096);
        async_cp16(gB + k0, lB);
        async_cp16(gB + 64 * D + k0, lB + 4096);
        __syncthreads();
        bf16x8 af[4], bfr[4];
        #pragma unroll
        for (int i = 0; i < 4; ++i) af[i] = *(const bf16x8*)(fragA + i * 512);
        #pragma unroll
        for (int j = 0; j < 4; ++j) bfr[j] = *(const bf16x8*)(fragB + j * 512);
        #pragma unroll
        for (int i = 0; i < 4; ++i)
            #pragma unroll
            for (int j = 0; j < 4; ++j)
                acc[i][j] = __builtin_amdgcn_mfma_f32_16x16x32_bf16(af[i], bfr[j], acc[i][j], 0, 0, 0);
        __syncthreads();
    }

    // epilogue: bias + tanh, store bf16. C/D layout: col = lane&15, row = quad*4+reg.
    float bcol[4];
    #pragma unroll
    for (int j = 0; j < 4; ++j) bcol[j] = bias[col0 + 64 * wc + 16 * j + lm];
    #pragma unroll
    for (int i = 0; i < 4; ++i) {
        #pragma unroll
        for (int r = 0; r < 4; ++r) {
            const int row = row0 + 64 * wr + 16 * i + 4 * g + r;
            #pragma unroll
            for (int j = 0; j < 4; ++j) {
                const int col = col0 + 64 * wc + 16 * j + lm;
                const float v = tanhf(acc[i][j][r] + bcol[j]);
                fb[(size_t)row * D + col] = f2bf(v);
            }
        }
    }
}

// ---------------------------------------------------------------------------
// Kernel 3b: row sum-of-squares of f (bf16 in, fp32 out)
__global__ void k_fsq(const unsigned short* __restrict__ fb,
                      float* __restrict__ fsq) {
    const int row = blockIdx.x;
    const int t = threadIdx.x;  // 256
    const unsigned u = ((const unsigned*)(fb + (size_t)row * D))[t];
    const float a = bf2f((unsigned short)(u & 0xffffu));
    const float b = bf2f((unsigned short)(u >> 16));
    float s = a * a + b * b;
    #pragma unroll
    for (int m = 1; m < 64; m <<= 1) s += __shfl_xor(s, m);
    __shared__ float ws4[4];
    if ((t & 63) == 0) ws4[t >> 6] = s;
    __syncthreads();
    if (t == 0) fsq[row] = ws4[0] + ws4[1] + ws4[2] + ws4[3];
}

// ---------------------------------------------------------------------------
// Kernel 4: fused cross-GEMM + online logsumexp (flash-style).
// Each block: 128 x-rows, one M-chunk of 1024 cols (8 subtiles of 128).
// Per subtile: full K=512 MFMA GEMM, then online (rowmax, rowsum) update.
__global__ __launch_bounds__(256, 2)
void k_cross(const unsigned short* __restrict__ xb,
             const unsigned short* __restrict__ fb,
             const float* __restrict__ xsq,
             const float* __restrict__ fsq,
             float* __restrict__ pmax,
             float* __restrict__ psum) {
    __shared__ unsigned short Ab[128 * 32];
    __shared__ unsigned short Bb[128 * 32];
    __shared__ float row_max[128], row_sum[128], row_xsq[128];
    __shared__ float wmax[128 * 2], wsum[128 * 2];

    const int tid = threadIdx.x;
    const int wave = tid >> 6;
    const int lane = tid & 63;
    const int wr = wave >> 1, wc = wave & 1;
    const int g = lane >> 4;
    const int lm = lane & 15;

    const int row0 = blockIdx.x * 128;
    const int chunk = blockIdx.y;

    if (tid < 128) {
        row_max[tid] = -__builtin_inff();
        row_sum[tid] = 0.f;
        row_xsq[tid] = xsq[row0 + tid];
    }
    __syncthreads();

    const unsigned short* gA = xb + (size_t)(row0 + (tid >> 2)) * D + (tid & 3) * 8;
    char* lA = ((char*)Ab) + wave * 1024;
    char* lB = ((char*)Bb) + wave * 1024;
    const unsigned short* fragA = Ab + (64 * wr + lm) * 32 + g * 8;
    const unsigned short* fragB = Bb + (64 * wc + lm) * 32 + g * 8;

    for (int st = 0; st < SUBTILES; ++st) {
        const int col0 = chunk * CHUNK_COLS + st * 128;
        const unsigned short* gB = fb + (size_t)(col0 + (tid >> 2)) * D + (tid & 3) * 8;

        floatx4 acc[4][4];
        const floatx4 zz = {0.f, 0.f, 0.f, 0.f};
        #pragma unroll
        for (int i = 0; i < 4; ++i)
            #pragma unroll
            for (int j = 0; j < 4; ++j) acc[i][j] = zz;

        for (int kt = 0; kt < 16; ++kt) {
            const int k0 = kt * 32;
            async_cp16(gA + k0, lA);
            async_cp16(gA + 64 * D + k0, lA + 4096);
            async_cp16(gB + k0, lB);
            async_cp16(gB + 64 * D + k0, lB + 4096);
            __syncthreads();
            bf16x8 af[4], bfr[4];
            #pragma unroll
            for (int i = 0; i < 4; ++i) af[i] = *(const bf16x8*)(fragA + i * 512);
            #pragma unroll
            for (int j = 0; j < 4; ++j) bfr[j] = *(const bf16x8*)(fragB + j * 512);
            #pragma unroll
            for (int i = 0; i < 4; ++i)
                #pragma unroll
                for (int j = 0; j < 4; ++j)
                    acc[i][j] = __builtin_amdgcn_mfma_f32_16x16x32_bf16(af[i], bfr[j], acc[i][j], 0, 0, 0);
            __syncthreads();
        }

        // ---- epilogue: m = cross - 0.5*(xsq + fsq); online logsumexp update
        float fsqc[4];
        #pragma unroll
        for (int j = 0; j < 4; ++j) fsqc[j] = fsq[col0 + 64 * wc + 16 * j + lm];

        float rmax[4][4];  // [i][reg]
        #pragma unroll
        for (int i = 0; i < 4; ++i) {
            #pragma unroll
            for (int r = 0; r < 4; ++r) {
                const int rl = 64 * wr + 16 * i + 4 * g + r;
                const float hx = 0.5f * row_xsq[rl];
                float mm = -__builtin_inff();
                #pragma unroll
                for (int j = 0; j < 4; ++j) {
                    const float mv = acc[i][j][r] - hx - 0.5f * fsqc[j];
                    acc[i][j][r] = mv;
                    mm = fmaxf(mm, mv);
                }
                rmax[i][r] = mm;
            }
        }
        // butterfly max across the 16-lane group (same rows, different cols)
        #pragma unroll
        for (int i = 0; i < 4; ++i)
            #pragma unroll
            for (int r = 0; r < 4; ++r) {
                float v = rmax[i][r];
                v = fmaxf(v, __shfl_xor(v, 1));
                v = fmaxf(v, __shfl_xor(v, 2));
                v = fmaxf(v, __shfl_xor(v, 4));
                v = fmaxf(v, __shfl_xor(v, 8));
                rmax[i][r] = v;
            }
        if (lm == 0) {
            #pragma unroll
            for (int i = 0; i < 4; ++i)
                #pragma unroll
                for (int r = 0; r < 4; ++r)
                    wmax[(64 * wr + 16 * i + 4 * g + r) * 2 + wc] = rmax[i][r];
        }
        __syncthreads();

        float rsum[4][4];
        #pragma unroll
        for (int i = 0; i < 4; ++i) {
            #pragma unroll
            for (int r = 0; r < 4; ++r) {
                const int rl = 64 * wr + 16 * i + 4 * g + r;
                const float nm = fmaxf(row_max[rl], fmaxf(wmax[rl * 2], wmax[rl * 2 + 1]));
                float s = 0.f;
                #pragma unroll
                for (int j = 0; j < 4; ++j) s += __expf(acc[i][j][r] - nm);
                rsum[i][r] = s;
            }
        }
        #pragma unroll
        for (int i = 0; i < 4; ++i)
            #pragma unroll
            for (int r = 0; r < 4; ++r) {
                float v = rsum[i][r];
                v += __shfl_xor(v, 1);
                v += __shfl_xor(v, 2);
                v += __shfl_xor(v, 4);
                v += __shfl_xor(v, 8);
                rsum[i][r] = v;
            }
        if (lm == 0) {
            #pragma unroll
            for (int i = 0; i < 4; ++i)
                #pragma unroll
                for (int r = 0; r < 4; ++r)
                    wsum[(64 * wr + 16 * i + 4 * g + r) * 2 + wc] = rsum[i][r];
        }
        __syncthreads();

        if (tid < 128) {
            const float om = row_max[tid];
            const float nm = fmaxf(om, fmaxf(wmax[tid * 2], wmax[tid * 2 + 1]));
            row_sum[tid] = row_sum[tid] * __expf(om - nm) + wsum[tid * 2] + wsum[tid * 2 + 1];
            row_max[tid] = nm;
        }
        __syncthreads();
    }

    if (tid < 128) {
        pmax[(size_t)(row0 + tid) * NCHUNK + chunk] = row_max[tid];
        psum[(size_t)(row0 + tid) * NCHUNK + chunk] = row_sum[tid];
    }
}

// ---------------------------------------------------------------------------
// Kernel 5: combine partials -> out = -sum_n lse_n (single block)
__global__ void k_finish(const float* __restrict__ pmax,
                         const float* __restrict__ psum,
                         float* __restrict__ out) {
    float acc = 0.f;
    for (int row = threadIdx.x; row < NROWS; row += 256) {
        const float* pm = pmax + (size_t)row * NCHUNK;
        const float* ps = psum + (size_t)row * NCHUNK;
        float gm = -__builtin_inff();
        #pragma unroll
        for (int c = 0; c < NCHUNK; ++c) gm = fmaxf(gm, pm[c]);
        float s = 0.f;
        #pragma unroll
        for (int c = 0; c < NCHUNK; ++c) s += ps[c] * __expf(pm[c] - gm);
        acc += gm + logf(s);
    }
    #pragma unroll
    for (int m = 1; m < 64; m <<= 1) acc += __shfl_xor(acc, m);
    __shared__ float ws4[4];
    if ((threadIdx.x & 63) == 0) ws4[threadIdx.x >> 6] = acc;
    __syncthreads();
    if (threadIdx.x == 0) out[0] = -(ws4[0] + ws4[1] + ws4[2] + ws4[3]);
}

// ---------------------------------------------------------------------------
extern "C" void kernel_launch(void* const* d_in, const int* in_sizes, int n_in,
                              void* d_out, int out_size, void* d_ws, size_t ws_size,
                              hipStream_t stream) {
    const float* x  = (const float*)d_in[0];   // (8192, 512)
    const float* mu = (const float*)d_in[1];   // (8192, 512)
    const float* W  = (const float*)d_in[2];   // (512, 512)
    const float* b  = (const float*)d_in[3];   // (512,)

    char* ws = (char*)d_ws;
    unsigned short* xb  = (unsigned short*)(ws);                    // 8 MB
    unsigned short* fb  = (unsigned short*)(ws + (8u << 20));       // 8 MB
    unsigned short* mub = (unsigned short*)(ws + (16u << 20));      // 8 MB
    unsigned short* Wb  = (unsigned short*)(ws + (24u << 20));      // 512 KB
    float* xsq  = (float*)(ws + (25u << 20));                       // 32 KB
    float* fsq  = xsq + NROWS;                                      // 32 KB
    float* pmax = fsq + MROWS;                                      // 256 KB
    float* psum = pmax + (size_t)NROWS * NCHUNK;                    // 256 KB

    hipLaunchKernelGGL(k_prep_x, dim3(NROWS), dim3(256), 0, stream, x, xb, xsq);
    hipLaunchKernelGGL(k_convert, dim3(4096), dim3(256), 0, stream, mu, mub, MROWS * D / 4);
    hipLaunchKernelGGL(k_convert, dim3(256), dim3(256), 0, stream, W, Wb, D * D / 4);
    hipLaunchKernelGGL(k_fgemm, dim3(MROWS / 128, D / 128), dim3(256), 0, stream, mub, Wb, b, fb);
    hipLaunchKernelGGL(k_fsq, dim3(MROWS), dim3(256), 0, stream, fb, fsq);
    hipLaunchKernelGGL(k_cross, dim3(NROWS / 128, NCHUNK), dim3(256), 0, stream,
                       xb, fb, xsq, fsq, pmax, psum);
    hipLaunchKernelGGL(k_finish, dim3(1), dim3(256), 0, stream, pmax, psum, (float*)d_out);
}